// Round 1
// baseline (83495.105 us; speedup 1.0000x reference)
//
#include <hip/hip_runtime.h>

#define BB 8
#define TT 2048
#define DD 64
#define HH 1024
#define OO 16
#define NBLK 16      // blocks per chain
#define ROWS 64      // rows per block
#define NCHAIN 16

// ws layout (floats):
// [0, 16)            barrier counters (u32, one per chain)  (padded to 256 floats)
// [256, 256+32768)   h double buffer: [2][16][1024] f32
// [33024, ...)       partial: [2*8][16][2048][16] f32  (33.5 MB)

__device__ __forceinline__ int swz_byte(int j) {
  int c = j >> 2;
  return ((c + (c >> 3)) << 4) + ((j & 3) << 2);
}

__global__ __launch_bounds__(512, 2) void esn_kernel(
    const float* __restrict__ u, const float* __restrict__ w,
    const float* __restrict__ w_in, const float* __restrict__ w_bias,
    const float* __restrict__ w_out, float* __restrict__ ws)
{
  __shared__ float h_sh[287 * 4];      // swizzled full h (1024 f32 + pads)
  __shared__ float hnew_sh[ROWS];
  __shared__ float wout_sh[ROWS * OO];

  const int tid  = threadIdx.x;
  const int lane = tid & 63;
  const int rg   = tid >> 6;       // wave id 0..7
  const int cg   = lane;           // col group 0..63 (16 cols each)
  const int bid  = blockIdx.x;
  const int chain = bid >> 4;      // 0..15
  const int g     = bid & 15;      // block-in-chain
  const int dir   = chain >> 3;    // 0 fwd, 1 bwd
  const int b     = chain & 7;
  const int row0  = g * ROWS;

  unsigned* cnt = (unsigned*)ws + chain;
  float* hbuf    = ws + 256;                       // [2][16][1024]
  float* partial = ws + 256 + 2 * NCHAIN * HH;

  // --- pin w fragment in registers: rows row0+rg*8+r, cols cg*16..cg*16+15
  float4 wreg[8][4];
  float  winreg[8];
#pragma unroll
  for (int r = 0; r < 8; ++r) {
    const float* wp = w + (size_t)(row0 + rg * 8 + r) * HH + cg * 16;
#pragma unroll
    for (int k = 0; k < 4; ++k) wreg[r][k] = ((const float4*)wp)[k];
    winreg[r] = w_in[(row0 + rg * 8 + r) * DD + cg];
  }
  const int   myrow    = rg * 8 + (lane & 7);       // local row this lane finalizes
  const float bias_r   = w_bias[row0 + myrow];
  const int   hold_off = swz_byte(row0 + myrow);

  // w_out slice for this block's rows -> LDS (rows are contiguous in w_out)
  {
    const float* wob = w_out + (size_t)(1 + dir * HH + row0) * OO;
    wout_sh[tid]       = wob[tid];
    wout_sh[tid + 512] = wob[tid + 512];
  }

  const int wj0 = swz_byte(tid), wj1 = swz_byte(tid + 512);
  const int rd_base = ((cg * 4 + (cg >> 1)) << 4);   // byte offset of this lane's 4 chunks

  const float* uptr = u + ((size_t)b * TT + (dir ? (TT - 1) : 0)) * DD + cg;
  const int    ustep = dir ? -DD : DD;
  float* pptr = partial + ((size_t)((dir * 8 + b) * NBLK + g)) * (TT * OO)
              + (dir ? (size_t)(TT - 1) * OO : 0);
  const int    pstep = dir ? -OO : OO;

  char* h_sh_b = (char*)h_sh;
  unsigned tgt = 0;

#pragma unroll 1
  for (int t = 0; t < TT; ++t) {
    const float* hb_r = hbuf + ((t & 1) * NCHAIN + chain) * HH;
    float*       hb_w = hbuf + ((((t + 1) & 1)) * NCHAIN + chain) * HH;

    // coherent (agent-scope) read of full h written by peer blocks on other XCDs
    float va = __hip_atomic_load(hb_r + tid,       __ATOMIC_ACQUIRE, __HIP_MEMORY_SCOPE_AGENT);
    float vb = __hip_atomic_load(hb_r + tid + 512, __ATOMIC_ACQUIRE, __HIP_MEMORY_SCOPE_AGENT);
    float uv = *uptr;
    *(float*)(h_sh_b + wj0) = va;
    *(float*)(h_sh_b + wj1) = vb;
    __syncthreads();

    float acc[8];
#pragma unroll
    for (int r = 0; r < 8; ++r) acc[r] = winreg[r] * uv;   // fused u_proj contribution
#pragma unroll
    for (int k = 0; k < 4; ++k) {
      float4 hv = *(const float4*)(h_sh_b + rd_base + k * 16);
#pragma unroll
      for (int r = 0; r < 8; ++r) {
        acc[r] += wreg[r][k].x * hv.x;
        acc[r] += wreg[r][k].y * hv.y;
        acc[r] += wreg[r][k].z * hv.z;
        acc[r] += wreg[r][k].w * hv.w;
      }
    }

    // rotated butterfly: lane ends with total for row (lane&7), summed over all 64 lanes
    bool s0 = lane & 1;
    float k0 = s0 ? acc[1] : acc[0], d0 = s0 ? acc[0] : acc[1];
    float k1 = s0 ? acc[3] : acc[2], d1 = s0 ? acc[2] : acc[3];
    float k2 = s0 ? acc[5] : acc[4], d2 = s0 ? acc[4] : acc[5];
    float k3 = s0 ? acc[7] : acc[6], d3 = s0 ? acc[6] : acc[7];
    float a0 = k0 + __shfl_xor(d0, 1);
    float a1 = k1 + __shfl_xor(d1, 1);
    float a2 = k2 + __shfl_xor(d2, 1);
    float a3 = k3 + __shfl_xor(d3, 1);
    bool s1 = lane & 2;
    float m0 = s1 ? a1 : a0, e0 = s1 ? a0 : a1;
    float m1 = s1 ? a3 : a2, e1 = s1 ? a2 : a3;
    float c0 = m0 + __shfl_xor(e0, 2);
    float c1 = m1 + __shfl_xor(e1, 2);
    bool s2 = lane & 4;
    float n0 = s2 ? c1 : c0, f0 = s2 ? c0 : c1;
    float tsum = n0 + __shfl_xor(f0, 4);
    tsum += __shfl_xor(tsum, 8);
    tsum += __shfl_xor(tsum, 16);
    tsum += __shfl_xor(tsum, 32);

    float z  = tsum + bias_r;
    float ex = __expf(2.0f * z);
    float th = 1.0f - 2.0f * __builtin_amdgcn_rcpf(ex + 1.0f);
    float hold = *(const float*)(h_sh_b + hold_off);
    float hn = 0.1f * hold + 0.9f * th;

    if (lane < 8) {
      __hip_atomic_store(hb_w + row0 + myrow, hn, __ATOMIC_RELAXED, __HIP_MEMORY_SCOPE_AGENT);
      hnew_sh[myrow] = hn;
    }
    __syncthreads();

    if (rg == 0) {   // per-step readout partial: this block's 64 rows -> 16 outputs
      int o = lane & 15, q = lane >> 4;
      float s = 0.f;
#pragma unroll
      for (int i = 0; i < 16; ++i)
        s += hnew_sh[q * 16 + i] * wout_sh[(q * 16 + i) * OO + o];
      s += __shfl_xor(s, 16);
      s += __shfl_xor(s, 32);
      if (lane < 16) pptr[lane] = s;
    }
    uptr += ustep;
    pptr += pstep;

    // per-chain barrier (monotonic counter, re-zeroed per call by memset)
    tgt += NBLK;
    __syncthreads();
    if (tid == 0) {
      __hip_atomic_fetch_add(cnt, 1u, __ATOMIC_ACQ_REL, __HIP_MEMORY_SCOPE_AGENT);
      while (__hip_atomic_load(cnt, __ATOMIC_ACQUIRE, __HIP_MEMORY_SCOPE_AGENT) < tgt) {}
    }
    __syncthreads();
  }
}

__global__ __launch_bounds__(256) void combine_kernel(
    const float* __restrict__ w_out, const float* __restrict__ partial,
    float* __restrict__ out)
{
  int idx = blockIdx.x * 256 + threadIdx.x;   // (b*2048+t)*16+o
  int o   = idx & 15;
  int bt  = idx >> 4;
  int b_  = bt >> 11;
  int t_  = bt & 2047;
  float s = w_out[o];   // bias row of w_out
#pragma unroll 1
  for (int dir = 0; dir < 2; ++dir)
#pragma unroll
    for (int g = 0; g < 16; ++g)
      s += partial[((size_t)((dir * 8 + b_) * 16 + g) * TT + t_) * OO + o];
  out[idx] = s;
}

extern "C" void kernel_launch(void* const* d_in, const int* in_sizes, int n_in,
                              void* d_out, int out_size, void* d_ws, size_t ws_size,
                              hipStream_t stream) {
  (void)in_sizes; (void)n_in; (void)out_size; (void)ws_size;
  const float* u      = (const float*)d_in[0];
  const float* w      = (const float*)d_in[1];
  const float* w_in   = (const float*)d_in[2];
  const float* w_bias = (const float*)d_in[3];
  const float* w_out  = (const float*)d_in[4];
  float* out = (float*)d_out;
  float* ws  = (float*)d_ws;

  // zero barrier counters + h double buffer (captured in the graph each replay)
  hipMemsetAsync(d_ws, 0, 256 * 4 + 2 * NCHAIN * HH * 4, stream);

  esn_kernel<<<dim3(256), dim3(512), 0, stream>>>(u, w, w_in, w_bias, w_out, ws);
  combine_kernel<<<dim3((BB * TT * OO) / 256), dim3(256), 0, stream>>>(
      w_out, ws + 256 + 2 * NCHAIN * HH, out);
}

// Round 2
// 7185.970 us; speedup vs baseline: 11.6192x; 11.6192x over previous
//
#include <hip/hip_runtime.h>

#define BB 8
#define TT 2048
#define DD 64
#define HH 1024
#define OO 16
#define NGRP 16      // groups = dir*8 + b
#define GBLK 16      // blocks per group (each owns 64 rows of w)
#define ROWS 64
#define KCH 16       // chains (time-chunks) per group
#define CHUNK 128    // useful steps per chunk
#define WASH 192     // washout steps (0.91^192 ~ 1.3e-8)
#define STEPS (CHUNK + WASH)

// ws layout (floats):
// [0, 1024)                      flags: [grp][16] u32, 64-float (256B) group spacing
// [1024, 1024+524288)            h buffers: [grp][2][KCH][HH] f32  (2 MB)
// [525312, +8.4M)                partial: [grp][GBLK][TT][OO] f32  (33.5 MB)

__device__ __forceinline__ int swz_byte(int j) {
  int c = j >> 2;
  return ((c + (c >> 3)) << 4) + ((j & 3) << 2);
}

__global__ __launch_bounds__(512, 2) void esn_kernel(
    const float* __restrict__ u, const float* __restrict__ w,
    const float* __restrict__ w_in, const float* __restrict__ w_bias,
    const float* __restrict__ w_out, float* __restrict__ ws)
{
  __shared__ float h_sh[2][1152];      // swizzled full h (1024 f32 + pads)
  __shared__ float hnew_sh[KCH][ROWS];
  __shared__ float wout_sh[ROWS * OO];

  const int tid  = threadIdx.x;
  const int lane = tid & 63;
  const int rg   = tid >> 6;        // wave 0..7
  const int cg   = lane;            // col group (16 cols each)
  const int bid  = blockIdx.x;
  const int grp  = bid & 15;        // group: blocks ≡ grp (mod 16) → one XCD
  const int blk  = bid >> 4;        // block-in-group 0..15
  const int dir  = grp >> 3;
  const int b    = grp & 7;
  const int row0 = blk * ROWS;

  unsigned* flags = (unsigned*)ws + grp * 64;            // [blk]
  float* hbase    = ws + 1024 + (size_t)grp * (2 * KCH * HH);
  float* partial  = ws + 1024 + (size_t)NGRP * 2 * KCH * HH;

  // --- pin w slice in registers: rows row0+rg*8+r, cols cg*16..cg*16+15
  float4 wreg[8][4];
  float  winreg[8];
#pragma unroll
  for (int r = 0; r < 8; ++r) {
    const float* wp = w + (size_t)(row0 + rg * 8 + r) * HH + cg * 16;
#pragma unroll
    for (int k = 0; k < 4; ++k) wreg[r][k] = ((const float4*)wp)[k];
    winreg[r] = w_in[(row0 + rg * 8 + r) * DD + cg];
  }
  // force-pin: opaque asm stops the compiler from re-loading w each step
#pragma unroll
  for (int r = 0; r < 8; ++r)
#pragma unroll
    for (int k = 0; k < 4; ++k)
      asm volatile("" : "+v"(wreg[r][k].x), "+v"(wreg[r][k].y),
                        "+v"(wreg[r][k].z), "+v"(wreg[r][k].w));

  const int   myrow    = rg * 8 + (lane & 7);
  const float bias_r   = w_bias[row0 + myrow];
  const int   hold_off = swz_byte(row0 + myrow);
  {
    const float* wob = w_out + (size_t)(1 + dir * HH + row0) * OO;
    wout_sh[tid]       = wob[tid];
    wout_sh[tid + 512] = wob[tid + 512];
  }
  const int wj0 = swz_byte(tid), wj1 = swz_byte(tid + 512);
  const int rd_base = ((cg * 4 + (cg >> 1)) << 4);

  float pva, pvb, pu;
  {  // prologue: chain-0 loads for step 0 (parity-0 buffer is zeroed)
    const float* hr = hbase;
    pva = __hip_atomic_load(hr + tid,       __ATOMIC_RELAXED, __HIP_MEMORY_SCOPE_AGENT);
    pvb = __hip_atomic_load(hr + tid + 512, __ATOMIC_RELAXED, __HIP_MEMORY_SCOPE_AGENT);
    int tu = dir ? (TT - 1) : 0;
    pu = u[((size_t)b * TT + tu) * DD + cg];
  }

#pragma unroll 1
  for (int i = 0; i < STEPS; ++i) {
    const float* hb_r = hbase + (i & 1) * (KCH * HH);
    float*       hb_w = hbase + ((i + 1) & 1) * (KCH * HH);

#pragma unroll 1
    for (int c = 0; c < KCH; ++c) {
      char* hsb = (char*)&h_sh[c & 1][0];
      *(float*)(hsb + wj0) = pva;
      *(float*)(hsb + wj1) = pvb;
      float uv = pu;
      __syncthreads();

      if (c + 1 < KCH) {   // prefetch next chain's h + u
        int ts = (c + 1) * CHUNK - WASH; ts = ts < 0 ? 0 : ts;
        int tau = ts + i;
        int tu = dir ? (TT - 1 - tau) : tau;
        const float* hr = hb_r + (c + 1) * HH;
        pva = __hip_atomic_load(hr + tid,       __ATOMIC_RELAXED, __HIP_MEMORY_SCOPE_AGENT);
        pvb = __hip_atomic_load(hr + tid + 512, __ATOMIC_RELAXED, __HIP_MEMORY_SCOPE_AGENT);
        pu  = u[((size_t)b * TT + tu) * DD + cg];
      }

      float acc[8];
#pragma unroll
      for (int r = 0; r < 8; ++r) acc[r] = winreg[r] * uv;
#pragma unroll
      for (int k = 0; k < 4; ++k) {
        float4 hv = *(const float4*)(hsb + rd_base + k * 16);
#pragma unroll
        for (int r = 0; r < 8; ++r) {
          acc[r] += wreg[r][k].x * hv.x;
          acc[r] += wreg[r][k].y * hv.y;
          acc[r] += wreg[r][k].z * hv.z;
          acc[r] += wreg[r][k].w * hv.w;
        }
      }

      // rotated butterfly: every lane ends with total for row (lane&7)
      bool s0 = lane & 1;
      float k0 = s0 ? acc[1] : acc[0], d0 = s0 ? acc[0] : acc[1];
      float k1 = s0 ? acc[3] : acc[2], d1 = s0 ? acc[2] : acc[3];
      float k2 = s0 ? acc[5] : acc[4], d2 = s0 ? acc[4] : acc[5];
      float k3 = s0 ? acc[7] : acc[6], d3 = s0 ? acc[6] : acc[7];
      float a0 = k0 + __shfl_xor(d0, 1);
      float a1 = k1 + __shfl_xor(d1, 1);
      float a2 = k2 + __shfl_xor(d2, 1);
      float a3 = k3 + __shfl_xor(d3, 1);
      bool s1 = lane & 2;
      float m0 = s1 ? a1 : a0, e0 = s1 ? a0 : a1;
      float m1 = s1 ? a3 : a2, e1 = s1 ? a2 : a3;
      float c0 = m0 + __shfl_xor(e0, 2);
      float c1 = m1 + __shfl_xor(e1, 2);
      bool s2 = lane & 4;
      float n0 = s2 ? c1 : c0, f0 = s2 ? c0 : c1;
      float tsum = n0 + __shfl_xor(f0, 4);
      tsum += __shfl_xor(tsum, 8);
      tsum += __shfl_xor(tsum, 16);
      tsum += __shfl_xor(tsum, 32);

      float z  = tsum + bias_r;
      float ex = __expf(2.0f * z);
      float th = 1.0f - 2.0f * __builtin_amdgcn_rcpf(ex + 1.0f);
      float hold = *(const float*)(hsb + hold_off);
      float hn = 0.1f * hold + 0.9f * th;

      if (lane < 8) {
        __hip_atomic_store(hb_w + c * HH + row0 + rg * 8 + lane, hn,
                           __ATOMIC_RELAXED, __HIP_MEMORY_SCOPE_AGENT);
        hnew_sh[c][rg * 8 + lane] = hn;
      }
    }
    __syncthreads();

    // readout partials: 2 chains per wave, only inside the useful window
#pragma unroll 1
    for (int cc = rg; cc < KCH; cc += 8) {
      int ts = cc * CHUNK - WASH; ts = ts < 0 ? 0 : ts;
      int tau = ts + i;
      int rel = tau - cc * CHUNK;
      if (rel >= 0 && rel < CHUNK) {
        int t_out = dir ? (TT - 1 - tau) : tau;
        int o = lane & 15, q = lane >> 4;
        float s = 0.f;
#pragma unroll
        for (int j = 0; j < 16; ++j)
          s += hnew_sh[cc][q * 16 + j] * wout_sh[(q * 16 + j) * OO + o];
        s += __shfl_xor(s, 16);
        s += __shfl_xor(s, 32);
        if (lane < 16)
          partial[((size_t)(grp * GBLK + blk) * TT + t_out) * OO + o] = s;
      }
    }

    // group barrier: per-block release-store flag, wave-0 polls 16 flags
    __syncthreads();
    if (tid == 0)
      __hip_atomic_store(flags + blk, (unsigned)(i + 1),
                         __ATOMIC_RELEASE, __HIP_MEMORY_SCOPE_AGENT);
    if (tid < 64) {
      const unsigned tgt = (unsigned)(i + 1);
      while (true) {
        unsigned v = __hip_atomic_load(flags + (lane & 15),
                                       __ATOMIC_ACQUIRE, __HIP_MEMORY_SCOPE_AGENT);
        if (__all(v >= tgt)) break;
        __builtin_amdgcn_s_sleep(1);
      }
    }
    __syncthreads();

    if (i + 1 < STEPS) {  // issue chain-0 loads for next step
      pva = __hip_atomic_load(hb_w + tid,       __ATOMIC_RELAXED, __HIP_MEMORY_SCOPE_AGENT);
      pvb = __hip_atomic_load(hb_w + tid + 512, __ATOMIC_RELAXED, __HIP_MEMORY_SCOPE_AGENT);
      int tau = i + 1;                 // chain 0: ts = 0
      int tu = dir ? (TT - 1 - tau) : tau;
      pu = u[((size_t)b * TT + tu) * DD + cg];
    }
  }
}

__global__ __launch_bounds__(256) void combine_kernel(
    const float* __restrict__ w_out, const float* __restrict__ partial,
    float* __restrict__ out)
{
  int idx = blockIdx.x * 256 + threadIdx.x;   // (b*2048+t)*16+o
  int o   = idx & 15;
  int bt  = idx >> 4;
  int b_  = bt >> 11;
  int t_  = bt & 2047;
  float s = w_out[o];   // bias row
#pragma unroll 1
  for (int dir = 0; dir < 2; ++dir)
#pragma unroll
    for (int g = 0; g < 16; ++g)
      s += partial[((size_t)((dir * 8 + b_) * 16 + g) * TT + t_) * OO + o];
  out[idx] = s;
}

extern "C" void kernel_launch(void* const* d_in, const int* in_sizes, int n_in,
                              void* d_out, int out_size, void* d_ws, size_t ws_size,
                              hipStream_t stream) {
  (void)in_sizes; (void)n_in; (void)out_size; (void)ws_size;
  const float* u      = (const float*)d_in[0];
  const float* w      = (const float*)d_in[1];
  const float* w_in   = (const float*)d_in[2];
  const float* w_bias = (const float*)d_in[3];
  const float* w_out  = (const float*)d_in[4];
  float* out = (float*)d_out;
  float* ws  = (float*)d_ws;

  // zero flags + h buffers (re-zeroed on every graph replay)
  hipMemsetAsync(d_ws, 0, (size_t)(1024 + NGRP * 2 * KCH * HH) * 4, stream);

  esn_kernel<<<dim3(NGRP * GBLK), dim3(512), 0, stream>>>(u, w, w_in, w_bias, w_out, ws);
  combine_kernel<<<dim3((BB * TT * OO) / 256), dim3(256), 0, stream>>>(
      w_out, ws + 1024 + (size_t)NGRP * 2 * KCH * HH, out);
}